// Round 8
// baseline (65641.681 us; speedup 1.0000x reference)
//
#include <hip/hip_runtime.h>

// NeuralCDEDecoder: B=512, T=257, IN=32, H=128, BN=256, OUT=64, K_SUB=4.
// R13: 16 rows/block x 8-way h-split. 256 blocks = 32 groups(16 rows) x 8
// h-octants, 1 block/CU. Rationale: R12 showed the stage is bound by the
// per-CU L2 weight stream (576KB/stage). Doubling rows/block amortizes
// W1+W2 over 2x work and halves the per-block W3 slice:
//   stream = W1(64K)+W2(128K)+W3oct(256K)-13 tiles cached(104K) ~= 344KB.
// Precision unchanged: 16 rows -> two 16-row hi/lo A-tiles; per-row math
// is bit-identical to R11/R12. Exchange = R11's RELAXED flag protocol,
// ring of 7 partners (R10-proven poll shape). All register arrays are
// statically indexed (manual nn=0/1 blocks; b-outer half-inner loops).
// fp32 state, hi/lo bf16 activations.

using short8   = __attribute__((ext_vector_type(8))) short;
using float4v  = __attribute__((ext_vector_type(4))) float;

__device__ unsigned short g_w1p[32768];
__device__ unsigned short g_w2p[65536];
__device__ unsigned short g_w3p[1048576];
__device__ unsigned short g_mwp[8192];
__device__ unsigned short g_swp[8192];

__device__ int   g_flag[256];                 // last stage posted per block
__device__ float g_zx[2 * 32 * 8 * 256];      // [parity][group][oct][16rows*16dims]

__global__ void reset_flags(){
  if (threadIdx.x < 256) g_flag[threadIdx.x] = -1;
}

__device__ __forceinline__ unsigned short* pack_dst(int which){
  switch (which){
    case 0:  return g_w1p;
    case 1:  return g_w2p;
    case 2:  return g_w3p;
    case 3:  return g_mwp;
    default: return g_swp;
  }
}

__device__ __forceinline__ float bf2f(unsigned short h){
  union { unsigned int u; float f; } v; v.u = ((unsigned int)h) << 16; return v.f;
}
__device__ __forceinline__ unsigned short f2bf(float f){
  union { float f; unsigned int u; } v; v.f = f;
  unsigned int u = v.u;
  return (unsigned short)((u + 0x7FFFu + ((u >> 16) & 1u)) >> 16);  // RNE
}
template<bool BF16> __device__ __forceinline__ float loadf(const void* p, long i){
  if constexpr (BF16) return bf2f(((const unsigned short*)p)[i]);
  else                return ((const float*)p)[i];
}
// t[0]=0.0 always; bytes 2..3 are high half of f32 t[0] (=0) or bf16 t[1] (!=0).
__device__ __forceinline__ bool input_is_bf16(const void* t){
  return ((const unsigned short*)t)[1] != 0;
}
__device__ __forceinline__ float tanh_f(float x){
  float e = __builtin_amdgcn_exp2f(x * 2.88539008177793f);          // e^{2x}
  return 1.f - 2.f * __builtin_amdgcn_rcpf(e + 1.f);
}
__device__ __forceinline__ float softplus_f(float x){
  if (x > 20.f) return x;
  float e = __builtin_amdgcn_exp2f(x * 1.44269504088896f);
  return __builtin_amdgcn_logf(1.f + e) * 0.693147180559945f;       // log2->ln
}
// Sum across each 16-lane row; full sum lands in lane 15 of the row (VALU DPP).
__device__ __forceinline__ float row_sum16(float v){
  int x;
  x = __builtin_amdgcn_update_dpp(0, __float_as_int(v), 0x118, 0xF, 0xF, true); // row_shr:8
  v += __int_as_float(x);
  x = __builtin_amdgcn_update_dpp(0, __float_as_int(v), 0x114, 0xF, 0xF, true); // row_shr:4
  v += __int_as_float(x);
  x = __builtin_amdgcn_update_dpp(0, __float_as_int(v), 0x112, 0xF, 0xF, true); // row_shr:2
  v += __int_as_float(x);
  x = __builtin_amdgcn_update_dpp(0, __float_as_int(v), 0x111, 0xF, 0xF, true); // row_shr:1
  v += __int_as_float(x);
  return v;
}

// Pack row-major [K,N] weight into fragment order:
// tile (nt,kt) -> 512 bf16 at ((nt*KT+kt)<<9); elem (lane,j) = W[kt*32+(lane>>4)*8+j][nt*16+(lane&15)]
template<bool BF16>
__global__ __launch_bounds__(256)
void pack_weight(const void* __restrict__ src, int which,
                 int K, int N, const void* __restrict__ tchk){
  if (input_is_bf16(tchk) != BF16) return;
  unsigned short* dst = pack_dst(which);
  const int KT = K >> 5;
  const long total = (long)(N >> 4) * KT * 512;
  for (long e = (long)blockIdx.x * blockDim.x + threadIdx.x; e < total;
       e += (long)gridDim.x * blockDim.x){
    int  r    = (int)(e & 511);
    long tile = e >> 9;
    int  kt   = (int)(tile % KT);
    int  nt   = (int)(tile / KT);
    int  ln   = r >> 3, j = r & 7;
    int  k    = (kt << 5) + ((ln >> 4) << 3) + j;
    int  n    = (nt << 4) + (ln & 15);
    long si   = (long)k * N + n;
    dst[e] = BF16 ? ((const unsigned short*)src)[si] : f2bf(((const float*)src)[si]);
  }
}

#define STRZ 136   // z buffer row stride (bf16), 32 rows = 2 halves x hi/lo x 8
#define STRH 264   // h buffer row stride (bf16), 32 rows
#define STRVW 20   // vf row stride (fp32), 16 rows x 16 own h
#define STRD 33    // dxdt row stride (fp32), 16 rows
#define W3C_NT 13  // W3 ntiles cached in LDS: slot s = local ntile 2s (s<13)

template<bool BF16>
__global__ __launch_bounds__(1024, 4)
void cde_main(const void* __restrict__ tin,  const void* __restrict__ z0in,
              const void* __restrict__ Xin,
              const void* __restrict__ b1in, const void* __restrict__ b2in,
              const void* __restrict__ b3in, const void* __restrict__ mbin,
              const void* __restrict__ sbin,
              void* __restrict__ outv)
{
  if (input_is_bf16(tin) != BF16) return;

  const unsigned short* __restrict__ w1p = g_w1p;
  const unsigned short* __restrict__ w2p = g_w2p;
  const unsigned short* __restrict__ w3p = g_w3p;
  const unsigned short* __restrict__ mwp = g_mwp;
  const unsigned short* __restrict__ swp = g_swp;

  __shared__ __align__(16) unsigned short bufZ [32 * STRZ];         //  8704B
  __shared__ __align__(16) unsigned short bufH1[32 * STRH];         // 16896B
  __shared__ __align__(16) unsigned short bufH2[32 * STRH];         // 16896B
  __shared__ __align__(16) float          vfs  [16 * STRVW];        //  1280B
  __shared__ __align__(16) float          dxs  [16 * STRD];         //  2112B
  __shared__ __align__(16) float          biasl[1152];              //  4608B
  __shared__ __align__(16) unsigned short w3c  [W3C_NT * 4096];     // 106496B

  const int tid  = threadIdx.x;
  const int lane = tid & 63;
  const int wv   = tid >> 6;          // wave 0..15
  const int c16  = lane & 15;         // MFMA A-row / B,D-col
  const int quad = lane >> 4;         // 0..3
  const int ho   = blockIdx.x & 7;    // h-octant: h in [ho*16, ho*16+16)
  const int grp  = blockIdx.x >> 3;   // row group 0..31
  const int m0   = grp * 16;          // batch-row base (16 rows per group)

  // biases -> LDS (fp32): b1|b2|b3oct|mb|sb
  for (int i = tid; i < 1152; i += 1024){
    float v;
    if      (i < 256)  v = loadf<BF16>(b1in, i);
    else if (i < 512)  v = loadf<BF16>(b2in, i - 256);
    else if (i < 1024) v = loadf<BF16>(b3in, ho * 512 + (i - 512));
    else if (i < 1088) v = loadf<BF16>(mbin, i - 1024);
    else               v = loadf<BF16>(sbin, i - 1088);
    biasl[i] = v;
  }

  // W3 LDS cache: slot s holds local ntile 2s (wave s's first tile), s<13.
  for (int e = tid * 8; e < W3C_NT * 4096; e += 1024 * 8){
    const int s = e >> 12;             // cached slot 0..12
    const int o = e & 4095;            // offset within tile (shorts)
    *(short8*)&w3c[e] =
      *(const short8*)&w3p[((long)(ho * 32 + 2 * s)) * 4096 + o];
  }

  // W1/W2 fragments (wave wv owns ntile wv of each layer)
  short8 w1f[4], w2f[8];
  {
    const unsigned short* p1 = w1p + ((long)(wv * 4) << 9) + lane * 8;
    #pragma unroll
    for (int kt = 0; kt < 4; ++kt) w1f[kt] = *(const short8*)(p1 + (kt << 9));
    const unsigned short* p2 = w2p + ((long)(wv * 8) << 9) + lane * 8;
    #pragma unroll
    for (int kt = 0; kt < 8; ++kt) w2f[kt] = *(const short8*)(p2 + (kt << 9));
  }

  // per-thread z-state: thread owns dim zd of batch rows zm and zm+8.
  const int  zm   = tid >> 7;         // 0..7
  const int  zd   = tid & 127;        // 0..127
  const int  q    = zd >> 4;          // octant this dim belongs to
  const bool own  = (q == ho);
  const int  d16  = zd & 15;
  float z0r = loadf<BF16>(z0in, (long)(m0 + zm    ) * 128 + zd);
  float z1r = loadf<BF16>(z0in, (long)(m0 + zm + 8) * 128 + zd);
  float zacc0 = 0.f, zacc1 = 0.f;
  {
    unsigned short h;
    h = f2bf(z0r);
    bufZ[( 2 * zm    ) * STRZ + zd] = h;
    bufZ[( 2 * zm + 1) * STRZ + zd] = f2bf(z0r - bf2f(h));
    h = f2bf(z1r);
    bufZ[(16 + 2 * zm    ) * STRZ + zd] = h;
    bufZ[(16 + 2 * zm + 1) * STRZ + zd] = f2bf(z1r - bf2f(h));
  }

  for (int ti = 0; ti < 256; ++ti){
    const float dt = loadf<BF16>(tin, ti + 1) - loadf<BF16>(tin, ti);
    const float hs = dt * 0.25f;                       // RK4 substep h
    if (tid < 512){
      const int m = tid >> 5, i = tid & 31;
      float xc = loadf<BF16>(Xin, ((long)(m0 + m) * 257 + ti    ) * 32 + i);
      float xn = loadf<BF16>(Xin, ((long)(m0 + m) * 257 + ti + 1) * 32 + i);
      dxs[m * STRD + i] = (xn - xc) / dt;
    }
    __syncthreads();                                   // dxs (and bufZ/bias/w3c) ready
    // ddA/ddB[half][s] = dxdt[row = half*8+quad*2+s][i = {0,1}*16 + c16]
    float ddA[2][2], ddB[2][2];
    #pragma unroll
    for (int half = 0; half < 2; ++half)
      #pragma unroll
      for (int s = 0; s < 2; ++s){
        ddA[half][s] = dxs[(half * 8 + quad * 2 + s) * STRD +      c16];
        ddB[half][s] = dxs[(half * 8 + quad * 2 + s) * STRD + 16 + c16];
      }

    for (int sub = 0; sub < 4; ++sub){
      for (int st = 0; st < 4; ++st){
        const int stg = (ti << 4) + (sub << 2) + st;   // global stage 0..4095
        const int par = stg & 1;
        __syncthreads();                               // [A] stage input in bufZ

        // -------- layer 1: relu(z @ W1 + b1)  K=128, two 16-row A-halves
        {
          const float bv = biasl[wv * 16 + c16];
          #pragma unroll
          for (int half = 0; half < 2; ++half){
            short8 a[4];
            #pragma unroll
            for (int kt = 0; kt < 4; ++kt)
              a[kt] = *(const short8*)&bufZ[(half * 16 + c16) * STRZ + kt * 32 + quad * 8];
            float4v acc = { 0.f, 0.f, 0.f, 0.f };
            #pragma unroll
            for (int kt = 0; kt < 4; ++kt)
              acc = __builtin_amdgcn_mfma_f32_16x16x32_bf16(a[kt], w1f[kt], acc, 0, 0, 0);
            #pragma unroll
            for (int s = 0; s < 2; ++s){
              float v = acc[2 * s] + acc[2 * s + 1] + bv;
              v = v > 0.f ? v : 0.f;
              unsigned short h = f2bf(v);
              const int row = half * 16 + quad * 4 + 2 * s;
              bufH1[ row      * STRH + wv * 16 + c16] = h;
              bufH1[(row + 1) * STRH + wv * 16 + c16] = f2bf(v - bf2f(h));
            }
          }
        }
        __syncthreads();                               // [B]

        // -------- layer 2: relu(h1 @ W2 + b2)  K=256, two A-halves
        {
          const float bv = biasl[256 + wv * 16 + c16];
          #pragma unroll
          for (int half = 0; half < 2; ++half){
            short8 a[8];
            #pragma unroll
            for (int kt = 0; kt < 8; ++kt)
              a[kt] = *(const short8*)&bufH1[(half * 16 + c16) * STRH + kt * 32 + quad * 8];
            float4v acc = { 0.f, 0.f, 0.f, 0.f };
            #pragma unroll
            for (int kt = 0; kt < 8; ++kt)
              acc = __builtin_amdgcn_mfma_f32_16x16x32_bf16(a[kt], w2f[kt], acc, 0, 0, 0);
            #pragma unroll
            for (int s = 0; s < 2; ++s){
              float v = acc[2 * s] + acc[2 * s + 1] + bv;
              v = v > 0.f ? v : 0.f;
              unsigned short h = f2bf(v);
              const int row = half * 16 + quad * 4 + 2 * s;
              bufH2[ row      * STRH + wv * 16 + c16] = h;
              bufH2[(row + 1) * STRH + wv * 16 + c16] = f2bf(v - bf2f(h));
            }
          }
        }
        __syncthreads();                               // [C]

        // -------- layer 3 + contraction: wave owns h_local = wv
        // (local ntiles 2wv [i 0..15, cached if wv<13] and 2wv+1 [streamed])
        {
          float t0[2][2], t1[2][2];                    // [half][s]
          { // tile A: ln = 2wv, i in [0,16)
            short8 b[8];
            if (wv < W3C_NT){
              const unsigned short* cp = &w3c[wv * 4096] + lane * 8;
              #pragma unroll
              for (int kt = 0; kt < 8; ++kt) b[kt] = *(const short8*)(cp + (kt << 9));
            } else {
              const unsigned short* wp = w3p + ((long)(ho * 32 + 2 * wv)) * 4096 + lane * 8;
              #pragma unroll
              for (int kt = 0; kt < 8; ++kt) b[kt] = *(const short8*)(wp + (kt << 9));
            }
            const float bv = biasl[512 + (2 * wv) * 16 + c16];
            #pragma unroll
            for (int half = 0; half < 2; ++half){
              short8 a[8];
              #pragma unroll
              for (int kt = 0; kt < 8; ++kt)
                a[kt] = *(const short8*)&bufH2[(half * 16 + c16) * STRH + kt * 32 + quad * 8];
              float4v acc = { 0.f, 0.f, 0.f, 0.f };
              #pragma unroll
              for (int kt = 0; kt < 8; ++kt)
                acc = __builtin_amdgcn_mfma_f32_16x16x32_bf16(a[kt], b[kt], acc, 0, 0, 0);
              #pragma unroll
              for (int s = 0; s < 2; ++s)
                t0[half][s] = tanh_f(acc[2 * s] + acc[2 * s + 1] + bv) * ddA[half][s];
            }
          }
          { // tile B: ln = 2wv+1, i in [16,32) (always streamed)
            short8 b[8];
            const unsigned short* wp = w3p + ((long)(ho * 32 + 2 * wv + 1)) * 4096 + lane * 8;
            #pragma unroll
            for (int kt = 0; kt < 8; ++kt) b[kt] = *(const short8*)(wp + (kt << 9));
            const float bv = biasl[512 + (2 * wv + 1) * 16 + c16];
            #pragma unroll
            for (int half = 0; half < 2; ++half){
              short8 a[8];
              #pragma unroll
              for (int kt = 0; kt < 8; ++kt)
                a[kt] = *(const short8*)&bufH2[(half * 16 + c16) * STRH + kt * 32 + quad * 8];
              float4v acc = { 0.f, 0.f, 0.f, 0.f };
              #pragma unroll
              for (int kt = 0; kt < 8; ++kt)
                acc = __builtin_amdgcn_mfma_f32_16x16x32_bf16(a[kt], b[kt], acc, 0, 0, 0);
              #pragma unroll
              for (int s = 0; s < 2; ++s)
                t1[half][s] = tanh_f(acc[2 * s] + acc[2 * s + 1] + bv) * ddB[half][s];
            }
          }
          #pragma unroll
          for (int half = 0; half < 2; ++half)
            #pragma unroll
            for (int s = 0; s < 2; ++s){
              float r = row_sum16(t0[half][s] + t1[half][s]);
              if (c16 == 15) vfs[(half * 8 + quad * 2 + s) * STRVW + wv] = r;
            }
        }
        __syncthreads();                               // [D] own-octant vfs ready

        // -------- RK4 combine (own octant, 2 rows/thread) + publish; receive
        if (own){
          {
            const float k = vfs[zm * STRVW + d16];
            float nin;
            if (st == 0){ zacc0 = z0r + (hs * (1.f/6.f)) * k; nin = z0r + 0.5f*hs*k; }
            else if (st == 1){ zacc0 += (hs * (1.f/3.f)) * k; nin = z0r + 0.5f*hs*k; }
            else if (st == 2){ zacc0 += (hs * (1.f/3.f)) * k; nin = z0r + hs*k; }
            else { z0r = zacc0 + (hs * (1.f/6.f)) * k; nin = z0r; }
            __hip_atomic_store((int*)&g_zx[((par * 32 + grp) * 8 + ho) * 256 + zm * 16 + d16],
                               __float_as_int(nin),
                               __ATOMIC_RELAXED, __HIP_MEMORY_SCOPE_AGENT);
            unsigned short h = f2bf(nin);
            bufZ[(2 * zm    ) * STRZ + zd] = h;
            bufZ[(2 * zm + 1) * STRZ + zd] = f2bf(nin - bf2f(h));
          }
          {
            const float k = vfs[(zm + 8) * STRVW + d16];
            float nin;
            if (st == 0){ zacc1 = z1r + (hs * (1.f/6.f)) * k; nin = z1r + 0.5f*hs*k; }
            else if (st == 1){ zacc1 += (hs * (1.f/3.f)) * k; nin = z1r + 0.5f*hs*k; }
            else if (st == 2){ zacc1 += (hs * (1.f/3.f)) * k; nin = z1r + hs*k; }
            else { z1r = zacc1 + (hs * (1.f/6.f)) * k; nin = z1r; }
            __hip_atomic_store((int*)&g_zx[((par * 32 + grp) * 8 + ho) * 256 + (zm + 8) * 16 + d16],
                               __float_as_int(nin),
                               __ATOMIC_RELAXED, __HIP_MEMORY_SCOPE_AGENT);
            unsigned short h = f2bf(nin);
            bufZ[(16 + 2 * zm    ) * STRZ + zd] = h;
            bufZ[(16 + 2 * zm + 1) * STRZ + zd] = f2bf(nin - bf2f(h));
          }
        }
        __syncthreads();                               // [E] vmcnt-drains publish stores
        // RELAXED post/poll (R11): no L2 invalidate/writeback storms.
        if (tid == 0)
          __hip_atomic_store(&g_flag[blockIdx.x], stg,
                             __ATOMIC_RELAXED, __HIP_MEMORY_SCOPE_AGENT);
        if (tid >= 1 && tid < 8){
          const int p = (grp << 3) | ((ho + tid) & 7);
          while (__hip_atomic_load(&g_flag[p],
                                   __ATOMIC_RELAXED, __HIP_MEMORY_SCOPE_AGENT) < stg)
            __builtin_amdgcn_s_sleep(2);
        }
        __syncthreads();                               // [F] partner slices visible
        if (!own){
          {
            int u = __hip_atomic_load(
                      (const int*)&g_zx[((par * 32 + grp) * 8 + q) * 256 + zm * 16 + d16],
                      __ATOMIC_RELAXED, __HIP_MEMORY_SCOPE_AGENT);
            float v = __int_as_float(u);
            unsigned short h = f2bf(v);
            bufZ[(2 * zm    ) * STRZ + zd] = h;
            bufZ[(2 * zm + 1) * STRZ + zd] = f2bf(v - bf2f(h));
          }
          {
            int u = __hip_atomic_load(
                      (const int*)&g_zx[((par * 32 + grp) * 8 + q) * 256 + (zm + 8) * 16 + d16],
                      __ATOMIC_RELAXED, __HIP_MEMORY_SCOPE_AGENT);
            float v = __int_as_float(u);
            unsigned short h = f2bf(v);
            bufZ[(16 + 2 * zm    ) * STRZ + zd] = h;
            bufZ[(16 + 2 * zm + 1) * STRZ + zd] = f2bf(v - bf2f(h));
          }
        }
      } // st
    } // sub

    __syncthreads();                                   // bufZ holds z(t[ti+1])
    // -------- decoder: oct0 -> mean, oct1 -> std; 8 waves (half = wv>>2)
    if (ho < 2 && wv < 8){
      const int  half  = wv >> 2;
      const int  nt    = wv & 3;
      const bool isStd = (ho == 1);
      short8 a[4];
      #pragma unroll
      for (int kt = 0; kt < 4; ++kt)
        a[kt] = *(const short8*)&bufZ[(half * 16 + c16) * STRZ + kt * 32 + quad * 8];
      const unsigned short* wp = (isStd ? swp : mwp) + ((long)(nt * 4) << 9) + lane * 8;
      short8 b[4];
      #pragma unroll
      for (int kt = 0; kt < 4; ++kt) b[kt] = *(const short8*)(wp + (kt << 9));
      float4v acc = { 0.f, 0.f, 0.f, 0.f };
      #pragma unroll
      for (int kt = 0; kt < 4; ++kt)
        acc = __builtin_amdgcn_mfma_f32_16x16x32_bf16(a[kt], b[kt], acc, 0, 0, 0);
      const float bv    = biasl[(isStd ? 1088 : 1024) + nt * 16 + c16];
      const long  obase = isStd ? 8388608L : 0L;       // B*(T-1)*OUT
      #pragma unroll
      for (int s = 0; s < 2; ++s){
        float v = acc[2 * s] + acc[2 * s + 1] + bv;
        if (isStd) v = softplus_f(v);
        long oi = obase + ((long)(m0 + half * 8 + quad * 2 + s) * 256 + ti) * 64
                        + nt * 16 + c16;
        if constexpr (BF16) ((unsigned short*)outv)[oi] = f2bf(v);
        else                ((float*)outv)[oi] = v;
      }
    }
  } // ti
}

extern "C" void kernel_launch(void* const* d_in, const int* in_sizes, int n_in,
                              void* d_out, int out_size, void* d_ws, size_t ws_size,
                              hipStream_t stream)
{
  const void* t  = d_in[0];
  const void* z0 = d_in[1];
  const void* X  = d_in[2];
  const void* W1 = d_in[3];
  const void* b1 = d_in[4];
  const void* W2 = d_in[5];
  const void* b2 = d_in[6];
  const void* W3 = d_in[7];
  const void* b3 = d_in[8];
  const void* mW = d_in[9];
  const void* mb = d_in[10];
  const void* sW = d_in[11];
  const void* sb = d_in[12];

  // Both dtype variants launched; each checks input dtype and the
  // non-matching one returns immediately (t[0]==0.0 discriminator).
  pack_weight<true ><<<256, 256, 0, stream>>>(W1, 0, 128,  256, t);
  pack_weight<true ><<<256, 256, 0, stream>>>(W2, 1, 256,  256, t);
  pack_weight<true ><<<512, 256, 0, stream>>>(W3, 2, 256, 4096, t);
  pack_weight<true ><<< 64, 256, 0, stream>>>(mW, 3, 128,   64, t);
  pack_weight<true ><<< 64, 256, 0, stream>>>(sW, 4, 128,   64, t);
  pack_weight<false><<<256, 256, 0, stream>>>(W1, 0, 128,  256, t);
  pack_weight<false><<<256, 256, 0, stream>>>(W2, 1, 256,  256, t);
  pack_weight<false><<<512, 256, 0, stream>>>(W3, 2, 256, 4096, t);
  pack_weight<false><<< 64, 256, 0, stream>>>(mW, 3, 128,   64, t);
  pack_weight<false><<< 64, 256, 0, stream>>>(sW, 4, 128,   64, t);

  reset_flags<<<1, 256, 0, stream>>>();               // stream-ordered before main

  cde_main<true ><<<256, 1024, 0, stream>>>(t, z0, X, b1, b2, b3, mb, sb, d_out);
  cde_main<false><<<256, 1024, 0, stream>>>(t, z0, X, b1, b2, b3, mb, sb, d_out);
  (void)in_sizes; (void)n_in; (void)out_size; (void)d_ws; (void)ws_size;
}

// Round 9
// 36870.206 us; speedup vs baseline: 1.7803x; 1.7803x over previous
//
#include <hip/hip_runtime.h>

// NeuralCDEDecoder: B=512, T=257, IN=32, H=128, BN=256, OUT=64, K_SUB=4.
// R14: R12 structure (4-way h-split, 256 blocks, relaxed flag protocol,
// 28.8ms) with ONE change: XCD-LOCAL exchange rings.
//   hq = blockIdx>>6, grp = blockIdx&63   (was hq=blockIdx&3, grp=>>2)
// Ring members {grp, grp+64, grp+128, grp+192} are all congruent mod 8 ->
// same XCD under round-robin dispatch. Flags + g_zx lines stay in that
// XCD's L2: polls are local hits, publish->receive RTT is L2 not fabric.
// (R13 post-mortem: 7-wide ring across 8 XCDs generated 113GB of EA poll
// traffic and congested the fabric -- FETCH 1.7GB -> 113GB, 2.3x slower.
// R11/R12's 4-wide consecutive-index rings also spanned 4 XCDs.)
// W3: 16/64 ntiles cached in LDS (one per wave); 48 streamed from L2.
// fp32 state, hi/lo bf16 activations.

using short8   = __attribute__((ext_vector_type(8))) short;
using float4v  = __attribute__((ext_vector_type(4))) float;

__device__ unsigned short g_w1p[32768];
__device__ unsigned short g_w2p[65536];
__device__ unsigned short g_w3p[1048576];
__device__ unsigned short g_mwp[8192];
__device__ unsigned short g_swp[8192];

__device__ int   g_flag[256];                 // last stage posted per block
__device__ float g_zx[2 * 64 * 4 * 256];      // [parity][group][quarter][8rows*32dims]

__global__ void reset_flags(){
  if (threadIdx.x < 256) g_flag[threadIdx.x] = -1;
}

__device__ __forceinline__ unsigned short* pack_dst(int which){
  switch (which){
    case 0:  return g_w1p;
    case 1:  return g_w2p;
    case 2:  return g_w3p;
    case 3:  return g_mwp;
    default: return g_swp;
  }
}

__device__ __forceinline__ float bf2f(unsigned short h){
  union { unsigned int u; float f; } v; v.u = ((unsigned int)h) << 16; return v.f;
}
__device__ __forceinline__ unsigned short f2bf(float f){
  union { float f; unsigned int u; } v; v.f = f;
  unsigned int u = v.u;
  return (unsigned short)((u + 0x7FFFu + ((u >> 16) & 1u)) >> 16);  // RNE
}
template<bool BF16> __device__ __forceinline__ float loadf(const void* p, long i){
  if constexpr (BF16) return bf2f(((const unsigned short*)p)[i]);
  else                return ((const float*)p)[i];
}
// t[0]=0.0 always; bytes 2..3 are high half of f32 t[0] (=0) or bf16 t[1] (!=0).
__device__ __forceinline__ bool input_is_bf16(const void* t){
  return ((const unsigned short*)t)[1] != 0;
}
__device__ __forceinline__ float tanh_f(float x){
  float e = __builtin_amdgcn_exp2f(x * 2.88539008177793f);          // e^{2x}
  return 1.f - 2.f * __builtin_amdgcn_rcpf(e + 1.f);
}
__device__ __forceinline__ float softplus_f(float x){
  if (x > 20.f) return x;
  float e = __builtin_amdgcn_exp2f(x * 1.44269504088896f);
  return __builtin_amdgcn_logf(1.f + e) * 0.693147180559945f;       // log2->ln
}
// Sum across each 16-lane row; full sum lands in lane 15 of the row (VALU DPP).
__device__ __forceinline__ float row_sum16(float v){
  int x;
  x = __builtin_amdgcn_update_dpp(0, __float_as_int(v), 0x118, 0xF, 0xF, true); // row_shr:8
  v += __int_as_float(x);
  x = __builtin_amdgcn_update_dpp(0, __float_as_int(v), 0x114, 0xF, 0xF, true); // row_shr:4
  v += __int_as_float(x);
  x = __builtin_amdgcn_update_dpp(0, __float_as_int(v), 0x112, 0xF, 0xF, true); // row_shr:2
  v += __int_as_float(x);
  x = __builtin_amdgcn_update_dpp(0, __float_as_int(v), 0x111, 0xF, 0xF, true); // row_shr:1
  v += __int_as_float(x);
  return v;
}

// Pack row-major [K,N] weight into fragment order:
// tile (nt,kt) -> 512 bf16 at ((nt*KT+kt)<<9); elem (lane,j) = W[kt*32+(lane>>4)*8+j][nt*16+(lane&15)]
template<bool BF16>
__global__ __launch_bounds__(256)
void pack_weight(const void* __restrict__ src, int which,
                 int K, int N, const void* __restrict__ tchk){
  if (input_is_bf16(tchk) != BF16) return;
  unsigned short* dst = pack_dst(which);
  const int KT = K >> 5;
  const long total = (long)(N >> 4) * KT * 512;
  for (long e = (long)blockIdx.x * blockDim.x + threadIdx.x; e < total;
       e += (long)gridDim.x * blockDim.x){
    int  r    = (int)(e & 511);
    long tile = e >> 9;
    int  kt   = (int)(tile % KT);
    int  nt   = (int)(tile / KT);
    int  ln   = r >> 3, j = r & 7;
    int  k    = (kt << 5) + ((ln >> 4) << 3) + j;
    int  n    = (nt << 4) + (ln & 15);
    long si   = (long)k * N + n;
    dst[e] = BF16 ? ((const unsigned short*)src)[si] : f2bf(((const float*)src)[si]);
  }
}

#define STRZ 136   // z buffer row stride (bf16), 16 rows = hi/lo x 8 batch rows
#define STRH 264   // h buffer row stride (bf16), 16 rows = hi/lo x 8
#define STRV 36    // vf row stride (fp32), 8 rows x 32 own dims
#define STRD 33    // dxdt row stride (fp32), 8 rows
#define W3C_NT 16  // W3 ntiles cached in LDS: local quarter-tiles {0,4,...,60}

template<bool BF16>
__global__ __launch_bounds__(1024, 4)
void cde_main(const void* __restrict__ tin,  const void* __restrict__ z0in,
              const void* __restrict__ Xin,
              const void* __restrict__ b1in, const void* __restrict__ b2in,
              const void* __restrict__ b3in, const void* __restrict__ mbin,
              const void* __restrict__ sbin,
              void* __restrict__ outv)
{
  if (input_is_bf16(tin) != BF16) return;

  const unsigned short* __restrict__ w1p = g_w1p;
  const unsigned short* __restrict__ w2p = g_w2p;
  const unsigned short* __restrict__ w3p = g_w3p;
  const unsigned short* __restrict__ mwp = g_mwp;
  const unsigned short* __restrict__ swp = g_swp;

  __shared__ __align__(16) unsigned short bufZ [16 * STRZ];
  __shared__ __align__(16) unsigned short bufH1[16 * STRH];
  __shared__ __align__(16) unsigned short bufH2[16 * STRH];
  __shared__ __align__(16) float          vfs  [ 8 * STRV];
  __shared__ __align__(16) float          dxs  [ 8 * STRD];
  __shared__ __align__(16) float          biasl[1664];              // b1|b2|b3q|mb|sb
  __shared__ __align__(16) unsigned short w3c  [W3C_NT * 4096];     // 128KB

  const int tid  = threadIdx.x;
  const int lane = tid & 63;
  const int wv   = tid >> 6;          // wave 0..15
  const int c16  = lane & 15;         // MFMA A-row / B,D-col
  const int quad = lane >> 4;         // 0..3
  // XCD-local ring: ring members {grp, grp+64, grp+128, grp+192} share
  // blockIdx mod 8 -> same XCD under round-robin dispatch.
  const int hq   = blockIdx.x >> 6;   // h-quarter: h in [hq*32, hq*32+32)
  const int grp  = blockIdx.x & 63;   // row group 0..63
  const int m0   = grp * 8;           // batch-row base (8 rows per group)

  // biases -> LDS (fp32); b3 only this block's quarter (1024 of 4096)
  for (int i = tid; i < 1664; i += 1024){
    float v;
    if      (i < 256)  v = loadf<BF16>(b1in, i);
    else if (i < 512)  v = loadf<BF16>(b2in, i - 256);
    else if (i < 1536) v = loadf<BF16>(b3in, hq * 1024 + (i - 512));
    else if (i < 1600) v = loadf<BF16>(mbin, i - 1536);
    else               v = loadf<BF16>(sbin, i - 1600);
    biasl[i] = v;
  }

  // W3 LDS cache: slot s holds quarter-tile s*4 (one cached tile per wave).
  for (int e = tid * 8; e < W3C_NT * 4096; e += 1024 * 8){
    const int s = e >> 12;             // cached slot 0..15
    const int o = e & 4095;            // offset within tile (shorts)
    *(short8*)&w3c[e] =
      *(const short8*)&w3p[(((long)(hq * 512 + s * 32)) << 9) + o];
  }

  // W1/W2 fragments (wave wv owns ntile wv of each layer)
  short8 w1f[4], w2f[8];
  {
    const unsigned short* p1 = w1p + ((long)(wv * 4) << 9) + lane * 8;
    #pragma unroll
    for (int kt = 0; kt < 4; ++kt) w1f[kt] = *(const short8*)(p1 + (kt << 9));
    const unsigned short* p2 = w2p + ((long)(wv * 8) << 9) + lane * 8;
    #pragma unroll
    for (int kt = 0; kt < 8; ++kt) w2f[kt] = *(const short8*)(p2 + (kt << 9));
  }

  // per-thread z-state: thread owns dim zd of batch sub-row zm.
  // Threads whose zd falls in this block's h-quarter do the RK4 update and
  // publish; the other 768 threads receive the partners' slices.
  const int  zm   = tid >> 7;         // 0..7
  const int  zd   = tid & 127;        // 0..127
  const bool own  = (zd >> 5) == hq;
  const int  xidx = zm * 32 + (zd & 31);
  float z = loadf<BF16>(z0in, (long)(m0 + zm) * 128 + zd);
  float zacc = 0.f;
  {
    unsigned short h = f2bf(z);
    bufZ[(2 * zm    ) * STRZ + zd] = h;
    bufZ[(2 * zm + 1) * STRZ + zd] = f2bf(z - bf2f(h));
  }

  for (int ti = 0; ti < 256; ++ti){
    const float dt = loadf<BF16>(tin, ti + 1) - loadf<BF16>(tin, ti);
    const float hs = dt * 0.25f;                       // RK4 substep h
    if (tid < 256){
      const int m = tid >> 5, i = tid & 31;
      float xc = loadf<BF16>(Xin, ((long)(m0 + m) * 257 + ti    ) * 32 + i);
      float xn = loadf<BF16>(Xin, ((long)(m0 + m) * 257 + ti + 1) * 32 + i);
      dxs[m * STRD + i] = (xn - xc) / dt;
    }
    __syncthreads();                                   // dxs (and bufZ/bias/w3c) ready
    // dd[ih][s] = dxdt[m = quad*2+s][i = ih*16 + c16]
    float dd[2][2];
    #pragma unroll
    for (int ih = 0; ih < 2; ++ih)
      #pragma unroll
      for (int s = 0; s < 2; ++s)
        dd[ih][s] = dxs[(quad * 2 + s) * STRD + ih * 16 + c16];

    for (int sub = 0; sub < 4; ++sub){
      for (int st = 0; st < 4; ++st){
        const int stg = (ti << 4) + (sub << 2) + st;   // global stage 0..4095
        const int par = stg & 1;
        __syncthreads();                               // [A] stage input in bufZ

        // -------- layer 1: relu(z @ W1 + b1)  K=128 N=256 (1 ntile/wave)
        {
          short8 a[4];
          #pragma unroll
          for (int kt = 0; kt < 4; ++kt)
            a[kt] = *(const short8*)&bufZ[c16 * STRZ + kt * 32 + quad * 8];
          float4v acc = { 0.f, 0.f, 0.f, 0.f };
          #pragma unroll
          for (int kt = 0; kt < 4; ++kt)
            acc = __builtin_amdgcn_mfma_f32_16x16x32_bf16(a[kt], w1f[kt], acc, 0, 0, 0);
          const float bv = biasl[wv * 16 + c16];
          #pragma unroll
          for (int s = 0; s < 2; ++s){
            float v = acc[2 * s] + acc[2 * s + 1] + bv;
            v = v > 0.f ? v : 0.f;
            unsigned short h = f2bf(v);
            const int row = quad * 4 + 2 * s;
            bufH1[ row      * STRH + wv * 16 + c16] = h;
            bufH1[(row + 1) * STRH + wv * 16 + c16] = f2bf(v - bf2f(h));
          }
        }
        __syncthreads();                               // [B]

        // -------- layer 2: relu(h1 @ W2 + b2)  K=256 N=256 (1 ntile/wave)
        {
          short8 a[8];
          #pragma unroll
          for (int kt = 0; kt < 8; ++kt)
            a[kt] = *(const short8*)&bufH1[c16 * STRH + kt * 32 + quad * 8];
          float4v acc = { 0.f, 0.f, 0.f, 0.f };
          #pragma unroll
          for (int kt = 0; kt < 8; ++kt)
            acc = __builtin_amdgcn_mfma_f32_16x16x32_bf16(a[kt], w2f[kt], acc, 0, 0, 0);
          const float bv = biasl[256 + wv * 16 + c16];
          #pragma unroll
          for (int s = 0; s < 2; ++s){
            float v = acc[2 * s] + acc[2 * s + 1] + bv;
            v = v > 0.f ? v : 0.f;
            unsigned short h = f2bf(v);
            const int row = quad * 4 + 2 * s;
            bufH2[ row      * STRH + wv * 16 + c16] = h;
            bufH2[(row + 1) * STRH + wv * 16 + c16] = f2bf(v - bf2f(h));
          }
        }
        __syncthreads();                               // [C]

        // -------- layer 3 + contraction (own h-quarter only):
        // wave owns local ntiles wv*4 .. wv*4+3; tile wv*4 is LDS-cached
        {
          short8 a[8];
          #pragma unroll
          for (int kt = 0; kt < 8; ++kt)
            a[kt] = *(const short8*)&bufH2[c16 * STRH + kt * 32 + quad * 8];

          #pragma unroll 1
          for (int j = 0; j < 4; j += 2){
            const int lnt = wv * 4 + j;
            float t0[2], t1[2];
            { // tile lnt: i in [0,16)  (j==0 -> cached in LDS slot wv)
              float4v acc = { 0.f, 0.f, 0.f, 0.f };
              if (j == 0){
                const unsigned short* cp = &w3c[wv * 4096] + lane * 8;
                #pragma unroll
                for (int kh = 0; kh < 2; ++kh){
                  short8 b[4];
                  #pragma unroll
                  for (int kt = 0; kt < 4; ++kt)
                    b[kt] = *(const short8*)(cp + ((kh * 4 + kt) << 9));
                  #pragma unroll
                  for (int kt = 0; kt < 4; ++kt)
                    acc = __builtin_amdgcn_mfma_f32_16x16x32_bf16(a[kh * 4 + kt], b[kt], acc, 0, 0, 0);
                }
              } else {
                const unsigned short* wp = w3p + (((long)(hq * 512 + lnt * 8)) << 9) + lane * 8;
                #pragma unroll
                for (int kh = 0; kh < 2; ++kh){
                  short8 b[4];
                  #pragma unroll
                  for (int kt = 0; kt < 4; ++kt)
                    b[kt] = *(const short8*)(wp + ((kh * 4 + kt) << 9));
                  #pragma unroll
                  for (int kt = 0; kt < 4; ++kt)
                    acc = __builtin_amdgcn_mfma_f32_16x16x32_bf16(a[kh * 4 + kt], b[kt], acc, 0, 0, 0);
                }
              }
              const float bv = biasl[512 + lnt * 16 + c16];
              #pragma unroll
              for (int s = 0; s < 2; ++s)
                t0[s] = tanh_f(acc[2 * s] + acc[2 * s + 1] + bv) * dd[0][s];
            }
            { // tile lnt+1: i in [16,32) + reduce + vf write (always streamed)
              const int nt = lnt + 1;
              float4v acc = { 0.f, 0.f, 0.f, 0.f };
              {
                const unsigned short* wp = w3p + (((long)(hq * 512 + nt * 8)) << 9) + lane * 8;
                #pragma unroll
                for (int kh = 0; kh < 2; ++kh){
                  short8 b[4];
                  #pragma unroll
                  for (int kt = 0; kt < 4; ++kt)
                    b[kt] = *(const short8*)(wp + ((kh * 4 + kt) << 9));
                  #pragma unroll
                  for (int kt = 0; kt < 4; ++kt)
                    acc = __builtin_amdgcn_mfma_f32_16x16x32_bf16(a[kh * 4 + kt], b[kt], acc, 0, 0, 0);
                }
              }
              const float bv = biasl[512 + nt * 16 + c16];
              #pragma unroll
              for (int s = 0; s < 2; ++s)
                t1[s] = tanh_f(acc[2 * s] + acc[2 * s + 1] + bv) * dd[1][s];
              const int hl = lnt >> 1;                 // local h index 0..31
              #pragma unroll
              for (int s = 0; s < 2; ++s){
                float r = row_sum16(t0[s] + t1[s]);
                if (c16 == 15) vfs[(quad * 2 + s) * STRV + hl] = r;
              }
            }
          }
        }
        __syncthreads();                               // [D] own-quarter vfs ready

        // -------- RK4 combine (own quarter) + publish; receive partner quarters
        if (own){
          const float k = vfs[zm * STRV + (zd & 31)];
          float nin;
          if (st == 0){
            zacc = z + (hs * (1.f / 6.f)) * k;
            nin  = z + 0.5f * hs * k;
          } else if (st == 1){
            zacc += (hs * (1.f / 3.f)) * k;
            nin   = z + 0.5f * hs * k;
          } else if (st == 2){
            zacc += (hs * (1.f / 3.f)) * k;
            nin   = z + hs * k;
          } else {
            z    = zacc + (hs * (1.f / 6.f)) * k;
            nin  = z;
          }
          __hip_atomic_store((int*)&g_zx[((par * 64 + grp) * 4 + hq) * 256 + xidx],
                             __float_as_int(nin),
                             __ATOMIC_RELAXED, __HIP_MEMORY_SCOPE_AGENT);
          unsigned short h = f2bf(nin);
          bufZ[(2 * zm    ) * STRZ + zd] = h;
          bufZ[(2 * zm + 1) * STRZ + zd] = f2bf(nin - bf2f(h));
        }
        __syncthreads();                               // [E] vmcnt-drains publish stores
        // RELAXED post/poll (R11): no L2 invalidate/writeback storms.
        // Partner blocks are on the SAME XCD -> flag lines are local L2 hits.
        if (tid == 0)
          __hip_atomic_store(&g_flag[blockIdx.x], stg,
                             __ATOMIC_RELAXED, __HIP_MEMORY_SCOPE_AGENT);
        if (tid < 3){
          const int p = (((hq + 1 + tid) & 3) << 6) | grp;
          while (__hip_atomic_load(&g_flag[p],
                                   __ATOMIC_RELAXED, __HIP_MEMORY_SCOPE_AGENT) < stg)
            __builtin_amdgcn_s_sleep(2);
        }
        __syncthreads();                               // [F] partner slices visible
        if (!own){
          const int q = zd >> 5;
          int u = __hip_atomic_load(
                    (const int*)&g_zx[((par * 64 + grp) * 4 + q) * 256 + xidx],
                    __ATOMIC_RELAXED, __HIP_MEMORY_SCOPE_AGENT);
          float v = __int_as_float(u);
          unsigned short h = f2bf(v);
          bufZ[(2 * zm    ) * STRZ + zd] = h;
          bufZ[(2 * zm + 1) * STRZ + zd] = f2bf(v - bf2f(h));
        }
      } // st
    } // sub

    __syncthreads();                                   // bufZ holds z(t[ti+1])
    // -------- decoder: hq==0 writes mean, hq==1 writes std (full z in bufZ)
    if (hq < 2 && wv < 4){
      short8 a[4];
      #pragma unroll
      for (int kt = 0; kt < 4; ++kt)
        a[kt] = *(const short8*)&bufZ[c16 * STRZ + kt * 32 + quad * 8];
      const int  nt    = wv;
      const bool isStd = (hq == 1);
      const unsigned short* wp = (isStd ? swp : mwp) + ((long)(nt * 4) << 9) + lane * 8;
      short8 b[4];
      #pragma unroll
      for (int kt = 0; kt < 4; ++kt) b[kt] = *(const short8*)(wp + (kt << 9));
      float4v acc = { 0.f, 0.f, 0.f, 0.f };
      #pragma unroll
      for (int kt = 0; kt < 4; ++kt)
        acc = __builtin_amdgcn_mfma_f32_16x16x32_bf16(a[kt], b[kt], acc, 0, 0, 0);
      const float bv    = biasl[(isStd ? 1600 : 1536) + nt * 16 + c16];
      const long  obase = isStd ? 8388608L : 0L;       // B*(T-1)*OUT
      #pragma unroll
      for (int s = 0; s < 2; ++s){
        float v = acc[2 * s] + acc[2 * s + 1] + bv;
        if (isStd) v = softplus_f(v);
        long oi = obase + ((long)(m0 + quad * 2 + s) * 256 + ti) * 64 + nt * 16 + c16;
        if constexpr (BF16) ((unsigned short*)outv)[oi] = f2bf(v);
        else                ((float*)outv)[oi] = v;
      }
    }
  } // ti
}

extern "C" void kernel_launch(void* const* d_in, const int* in_sizes, int n_in,
                              void* d_out, int out_size, void* d_ws, size_t ws_size,
                              hipStream_t stream)
{
  const void* t  = d_in[0];
  const void* z0 = d_in[1];
  const void* X  = d_in[2];
  const void* W1 = d_in[3];
  const void* b1 = d_in[4];
  const void* W2 = d_in[5];
  const void* b2 = d_in[6];
  const void* W3 = d_in[7];
  const void* b3 = d_in[8];
  const void* mW = d_in[9];
  const void* mb = d_in[10];
  const void* sW = d_in[11];
  const void* sb = d_in[12];

  // Both dtype variants launched; each checks input dtype and the
  // non-matching one returns immediately (t[0]==0.0 discriminator).
  pack_weight<true ><<<256, 256, 0, stream>>>(W1, 0, 128,  256, t);
  pack_weight<true ><<<256, 256, 0, stream>>>(W2, 1, 256,  256, t);
  pack_weight<true ><<<512, 256, 0, stream>>>(W3, 2, 256, 4096, t);
  pack_weight<true ><<< 64, 256, 0, stream>>>(mW, 3, 128,   64, t);
  pack_weight<true ><<< 64, 256, 0, stream>>>(sW, 4, 128,   64, t);
  pack_weight<false><<<256, 256, 0, stream>>>(W1, 0, 128,  256, t);
  pack_weight<false><<<256, 256, 0, stream>>>(W2, 1, 256,  256, t);
  pack_weight<false><<<512, 256, 0, stream>>>(W3, 2, 256, 4096, t);
  pack_weight<false><<< 64, 256, 0, stream>>>(mW, 3, 128,   64, t);
  pack_weight<false><<< 64, 256, 0, stream>>>(sW, 4, 128,   64, t);

  reset_flags<<<1, 256, 0, stream>>>();               // stream-ordered before main

  cde_main<true ><<<256, 1024, 0, stream>>>(t, z0, X, b1, b2, b3, mb, sb, d_out);
  cde_main<false><<<256, 1024, 0, stream>>>(t, z0, X, b1, b2, b3, mb, sb, d_out);
  (void)in_sizes; (void)n_in; (void)out_size; (void)d_ws; (void)ws_size;
}